// Round 7
// baseline (1510.017 us; speedup 1.0000x reference)
//
#include <hip/hip_runtime.h>

#define N_NODES_C 200000
#define N_EDGES_C 3200000
#define NUM_GRAPHS_C 1024
#define NBKT 3125          // 200000 / 64, exact
#define BKT_SHIFT 6        // 64 nodes per bucket

// ---------------- CSR build, bucketed ----------------

// (1) per-block LDS histogram of edge buckets -> global bcount
__global__ __launch_bounds__(256) void k_bhist(const int* __restrict__ dst, int* __restrict__ bcount, int E){
  __shared__ int hist[NBKT];
  for (int i = threadIdx.x; i < NBKT; i += 256) hist[i] = 0;
  __syncthreads();
  for (int e = blockIdx.x*256 + threadIdx.x; e < E; e += gridDim.x*256)
    atomicAdd(&hist[dst[e] >> BKT_SHIFT], 1);
  __syncthreads();
  for (int i = threadIdx.x; i < NBKT; i += 256){
    int v = hist[i];
    if (v) atomicAdd(&bcount[i], v);
  }
}

// (2) exclusive scan of 3125 bucket counts; also zero bfill, set rowptr[N]
__global__ __launch_bounds__(1024) void k_bscan(const int* __restrict__ bcount, int* __restrict__ bbase,
                                                int* __restrict__ bfill, int* __restrict__ rowptr){
  __shared__ int s[1024];
  int t = threadIdx.x;
  int v0=0,v1=0,v2=0,v3=0, sum;
  int i0 = t*4;
  if (i0+0 < NBKT) v0 = bcount[i0+0];
  if (i0+1 < NBKT) v1 = bcount[i0+1];
  if (i0+2 < NBKT) v2 = bcount[i0+2];
  if (i0+3 < NBKT) v3 = bcount[i0+3];
  sum = v0+v1+v2+v3;
  s[t] = sum;
  __syncthreads();
  #pragma unroll
  for (int off = 1; off < 1024; off <<= 1){
    int u = (t >= off) ? s[t - off] : 0;
    __syncthreads();
    s[t] += u;
    __syncthreads();
  }
  int run = s[t] - sum;   // exclusive
  if (i0+0 < NBKT){ bbase[i0+0] = run; bfill[i0+0] = 0; run += v0; }
  if (i0+1 < NBKT){ bbase[i0+1] = run; bfill[i0+1] = 0; run += v1; }
  if (i0+2 < NBKT){ bbase[i0+2] = run; bfill[i0+2] = 0; run += v2; }
  if (i0+3 < NBKT){ bbase[i0+3] = run; bfill[i0+3] = 0; run += v3; }
  if (t == 0) rowptr[N_NODES_C] = N_EDGES_C;
}

// (3) scatter edges into bucket-contiguous pairbuf; pack (dst&63)<<18 | src
__global__ __launch_bounds__(256) void k_bucketize(const int* __restrict__ src, const int* __restrict__ dst,
                                                   const int* __restrict__ bbase, int* __restrict__ bfill,
                                                   unsigned* __restrict__ pairbuf, int E){
  int e = blockIdx.x*256 + threadIdx.x;
  if (e >= E) return;
  int d = dst[e];
  int b = d >> BKT_SHIFT;
  int pos = atomicAdd(&bfill[b], 1);
  pairbuf[bbase[b] + pos] = ((unsigned)(d & 63) << 18) | (unsigned)src[e];
}

// (4) per-bucket: local degree count (LDS), local scan, write rowptr, scatter colb
__global__ __launch_bounds__(256) void k_bfinal(const unsigned* __restrict__ pairbuf,
                                                const int* __restrict__ bcount, const int* __restrict__ bbase,
                                                int* __restrict__ rowptr, int* __restrict__ colb){
  __shared__ int ldeg[64];
  __shared__ int lbase[64];
  __shared__ int lfill[64];
  int b = blockIdx.x;
  int cnt = bcount[b], base = bbase[b];
  int t = threadIdx.x;
  if (t < 64){ ldeg[t] = 0; lfill[t] = 0; }
  __syncthreads();
  for (int k = t; k < cnt; k += 256)
    atomicAdd(&ldeg[pairbuf[base + k] >> 18], 1);
  __syncthreads();
  if (t == 0){
    int run = 0;
    for (int i = 0; i < 64; i++){ lbase[i] = run; run += ldeg[i]; }
  }
  __syncthreads();
  if (t < 64) rowptr[(b << BKT_SHIFT) + t] = base + lbase[t];
  for (int k = t; k < cnt; k += 256){
    unsigned v = pairbuf[base + k];
    int ld = v >> 18;
    int pos = atomicAdd(&lfill[ld], 1);
    colb[base + lbase[ld] + pos] = (int)(v & 0x3FFFFu);
  }
}

// ---------------- node embedding ----------------
__global__ __launch_bounds__(256) void k_embed(const int* __restrict__ x, const float* __restrict__ emb,
                                               float* __restrict__ h, int total){
  int idx = blockIdx.x*256 + threadIdx.x;
  if (idx < total){
    int node = idx >> 6;
    h[idx] = emb[x[node]*64 + (idx & 63)];
  }
}

// ---------------- gather: z[i] = h[i] + sum_{j in N(i)} h[j] ----------------
// wave per node; lane = (edge_slot 0..3) x (float4 chunk 0..15); 32 edges in flight/iter.
__global__ __launch_bounds__(256) void k_gather(const float4* __restrict__ h4, const int* __restrict__ rowptr,
                                                const int* __restrict__ colb, float4* __restrict__ z4, int n){
  int wid   = __builtin_amdgcn_readfirstlane((int)(threadIdx.x >> 6));
  int lane  = threadIdx.x & 63;
  int eslot = lane >> 4;      // 0..3
  int c4    = lane & 15;      // float4 chunk
  int i = blockIdx.x*4 + wid;
  if (i >= n) return;
  int rs = rowptr[i], re = rowptr[i+1];
  float4 acc = make_float4(0.f, 0.f, 0.f, 0.f);
  for (int p = rs; p < re; p += 32){
    #pragma unroll
    for (int g = 0; g < 8; ++g){
      int e = p + g*4 + eslot;
      if (e < re){
        int c = colb[e];                      // broadcast within 16-lane group
        float4 v = h4[(size_t)c*16 + c4];
        acc.x += v.x; acc.y += v.y; acc.z += v.z; acc.w += v.w;
      }
    }
  }
  #pragma unroll
  for (int m = 16; m <= 32; m <<= 1){
    acc.x += __shfl_xor(acc.x, m, 64);
    acc.y += __shfl_xor(acc.y, m, 64);
    acc.z += __shfl_xor(acc.z, m, 64);
    acc.w += __shfl_xor(acc.w, m, 64);
  }
  if (eslot == 0){
    float4 s = h4[(size_t)i*16 + c4];
    acc.x += s.x; acc.y += s.y; acc.z += s.z; acc.w += s.w;
    z4[(size_t)i*16 + c4] = acc;
  }
}

// ---------------- per-node MLP: z <- relu(z@W1+b1)@W2+b2, in place ----------------
// thread per node; all register arrays compile-time indexed; no LDS.
__global__ __launch_bounds__(256) void k_mlp(float* __restrict__ z,
                                             const float* __restrict__ w1, const float* __restrict__ b1,
                                             const float* __restrict__ w2, const float* __restrict__ b2, int n){
  int node = blockIdx.x*256 + threadIdx.x;
  if (node >= n) return;
  float* zrow = z + (size_t)node*64;
  float t[64];
  #pragma unroll
  for (int j = 0; j < 64; j++) t[j] = b1[j];
  for (int kb = 0; kb < 16; ++kb){
    float4 c = *reinterpret_cast<const float4*>(zrow + kb*4);
    const float* wr = w1 + kb*256;            // rows 4kb..4kb+3 of W1 (uniform -> s_load)
    #pragma unroll
    for (int j = 0; j < 64; j++)
      t[j] += c.x*wr[j] + c.y*wr[64+j] + c.z*wr[128+j] + c.w*wr[192+j];
  }
  #pragma unroll
  for (int j = 0; j < 64; j++) t[j] = fmaxf(t[j], 0.f);
  for (int jb = 0; jb < 16; ++jb){
    const float* wc = w2 + jb*4;              // column block jb (uniform -> s_load)
    float4 a = make_float4(b2[jb*4], b2[jb*4+1], b2[jb*4+2], b2[jb*4+3]);
    #pragma unroll
    for (int k = 0; k < 64; k++){
      a.x += t[k]*wc[k*64+0];
      a.y += t[k]*wc[k*64+1];
      a.z += t[k]*wc[k*64+2];
      a.w += t[k]*wc[k*64+3];
    }
    *reinterpret_cast<float4*>(zrow + jb*4) = a;
  }
}

// ---------------- global_add_pool (batch is sorted) ----------------
__global__ __launch_bounds__(256) void k_pool(const float* __restrict__ h, const int* __restrict__ batch,
                                              float* __restrict__ g, int n, int ng){
  int wid  = __builtin_amdgcn_readfirstlane((int)(threadIdx.x >> 6));
  int lane = threadIdx.x & 63;
  int gi = blockIdx.x*4 + wid;
  if (gi >= ng) return;
  int lo = 0, hi = n;
  while (lo < hi){ int m = (lo + hi) >> 1; if (batch[m] < gi) lo = m + 1; else hi = m; }
  int s = lo;
  hi = n;
  while (lo < hi){ int m = (lo + hi) >> 1; if (batch[m] < gi + 1) lo = m + 1; else hi = m; }
  int t = lo;
  float a0=0,a1=0,a2=0,a3=0;
  for (int p = s; p < t; p += 4){
    a0 += h[(size_t)p*64 + lane];
    if (p+1 < t) a1 += h[(size_t)(p+1)*64 + lane];
    if (p+2 < t) a2 += h[(size_t)(p+2)*64 + lane];
    if (p+3 < t) a3 += h[(size_t)(p+3)*64 + lane];
  }
  g[(size_t)gi*64 + lane] = (a0+a1) + (a2+a3);
}

// ---------------- readout MLP 64->32->16->1 ----------------
__global__ __launch_bounds__(256) void k_readout(const float* __restrict__ g,
                                                 const float* __restrict__ w1, const float* __restrict__ b1,
                                                 const float* __restrict__ w2, const float* __restrict__ b2,
                                                 const float* __restrict__ w3, const float* __restrict__ b3,
                                                 float* __restrict__ out, int ng){
  int gi = blockIdx.x*256 + threadIdx.x;
  if (gi >= ng) return;
  const float* gr = g + (size_t)gi*64;
  float a1[32];
  #pragma unroll
  for (int j = 0; j < 32; j++) a1[j] = b1[j];
  for (int k = 0; k < 64; k++){
    float gv = gr[k];
    const float* wr = w1 + k*32;
    #pragma unroll
    for (int j = 0; j < 32; j++) a1[j] += gv * wr[j];
  }
  float a2[16];
  #pragma unroll
  for (int j = 0; j < 16; j++) a2[j] = b2[j];
  #pragma unroll
  for (int k = 0; k < 32; k++){
    float t = fmaxf(a1[k], 0.f);
    const float* wr = w2 + k*16;
    #pragma unroll
    for (int j = 0; j < 16; j++) a2[j] += t * wr[j];
  }
  float r = b3[0];
  #pragma unroll
  for (int k = 0; k < 16; k++) r += fmaxf(a2[k], 0.f) * w3[k];
  out[gi] = r;
}

extern "C" void kernel_launch(void* const* d_in, const int* in_sizes, int n_in,
                              void* d_out, int out_size, void* d_ws, size_t ws_size,
                              hipStream_t stream){
  const int N = N_NODES_C, E = N_EDGES_C, G = NUM_GRAPHS_C;
  const int*   x     = (const int*)d_in[0];
  const int*   ei    = (const int*)d_in[1];   // [2,E]: src = ei[0..E), dst = ei[E..2E)
  const int*   batch = (const int*)d_in[3];
  const float* nemb  = (const float*)d_in[4];
  const float* cw1   = (const float*)d_in[6];
  const float* cb1   = (const float*)d_in[7];
  const float* cw2   = (const float*)d_in[8];
  const float* cb2   = (const float*)d_in[9];
  const float* mw1   = (const float*)d_in[10];
  const float* mb1   = (const float*)d_in[11];
  const float* mw2   = (const float*)d_in[12];
  const float* mb2   = (const float*)d_in[13];
  const float* mw3   = (const float*)d_in[14];
  const float* mb3   = (const float*)d_in[15];
  float* out = (float*)d_out;

  // Workspace budget: round-1 layout used ~118.7 MB and passed (=> ws_size >=
  // that). Keep this layout strictly smaller: pairbuf ALIASES hB (pairbuf is
  // dead after k_bfinal; hB is first fully overwritten by layer-0 k_gather).
  char* cur = (char*)d_ws;
  auto take = [&](size_t bytes)->char*{
    char* p = cur; cur += (bytes + 255) & ~(size_t)255; return p;
  };
  int*      bcount  = (int*)  take((size_t)NBKT*4);
  int*      bbase   = (int*)  take((size_t)NBKT*4);
  int*      bfill   = (int*)  take((size_t)NBKT*4);
  int*      rowptr  = (int*)  take((size_t)(N+1)*4);
  int*      colb    = (int*)  take((size_t)(E+8)*4);
  float*    hA      = (float*)take((size_t)N*64*4);
  float*    hB      = (float*)take((size_t)N*64*4);
  float*    gbuf    = (float*)take((size_t)G*64*4);
  unsigned* pairbuf = (unsigned*)hB;                // alias: E*4 = 12.8MB <= 51.2MB

  hipMemsetAsync(bcount, 0, (size_t)NBKT*4, stream);

  const int EB = (E + 255)/256;                     // 12500
  k_bhist    <<<128, 256, 0, stream>>>(ei + E, bcount, E);
  k_bscan    <<<1, 1024, 0, stream>>>(bcount, bbase, bfill, rowptr);
  k_bucketize<<<EB, 256, 0, stream>>>(ei, ei + E, bbase, bfill, pairbuf, E);
  k_bfinal   <<<NBKT, 256, 0, stream>>>(pairbuf, bcount, bbase, rowptr, colb);
  k_embed    <<<(N*64 + 255)/256, 256, 0, stream>>>(x, nemb, hA, N*64);

  float* A = hA; float* B = hB;
  for (int l = 0; l < 4; l++){
    k_gather<<<(N + 3)/4, 256, 0, stream>>>((const float4*)A, rowptr, colb, (float4*)B, N);
    k_mlp   <<<(N + 255)/256, 256, 0, stream>>>(B, cw1 + l*4096, cb1 + l*64,
                                                cw2 + l*4096, cb2 + l*64, N);
    float* t2 = A; A = B; B = t2;
  }
  k_pool   <<<(G + 3)/4, 256, 0, stream>>>(A, batch, gbuf, N, G);
  k_readout<<<(G + 255)/256, 256, 0, stream>>>(gbuf, mw1, mb1, mw2, mb2, mw3, mb3, out, G);
}

// Round 10
// 1283.383 us; speedup vs baseline: 1.1766x; 1.1766x over previous
//
#include <hip/hip_runtime.h>

#define N_NODES_C 200000
#define N_EDGES_C 3200000
#define NUM_GRAPHS_C 1024
#define CB_BITS 10
#define CBKT 196           // ceil(200000 / 1024)
#define SUBCH 4096

// ---------------- CSR build: coarse-bucket LDS-staged binning ----------------

// (1) histogram of coarse buckets -> cbase (counts)
__global__ __launch_bounds__(256) void k_chist(const int* __restrict__ dst, int* __restrict__ cbase, int E){
  __shared__ int hist[CBKT];
  for (int i = threadIdx.x; i < CBKT; i += 256) hist[i] = 0;
  __syncthreads();
  for (int e = blockIdx.x*256 + threadIdx.x; e < E; e += gridDim.x*256)
    atomicAdd(&hist[dst[e] >> CB_BITS], 1);
  __syncthreads();
  for (int i = threadIdx.x; i < CBKT; i += 256){
    int v = hist[i];
    if (v) atomicAdd(&cbase[i], v);
  }
}

// (2) exclusive scan of 196 counts; cbase <- bases, gfill <- bases, sentinels
__global__ __launch_bounds__(256) void k_cscan(int* __restrict__ cbase, int* __restrict__ gfill,
                                               int* __restrict__ rowptr){
  __shared__ int s[256];
  int t = threadIdx.x;
  int v = (t < CBKT) ? cbase[t] : 0;
  s[t] = v;
  __syncthreads();
  #pragma unroll
  for (int off = 1; off < 256; off <<= 1){
    int u = (t >= off) ? s[t - off] : 0;
    __syncthreads();
    s[t] += u;
    __syncthreads();
  }
  int excl = s[t] - v;
  if (t < CBKT){ cbase[t] = excl; gfill[t] = excl; }
  if (t == 0){ cbase[CBKT] = N_EDGES_C; rowptr[N_NODES_C] = N_EDGES_C; }
}

// (3) LDS-staged binning: each block reorders a 4096-edge sub-chunk by coarse
// bucket and writes per-bucket runs coalesced (each 64B line produced by one
// block's contiguous store -> no cross-XCD frontier ping-pong).
__global__ __launch_bounds__(256) void k_cbin(const int* __restrict__ src, const int* __restrict__ dst,
                                              int* __restrict__ gfill, unsigned* __restrict__ pairbuf, int E){
  __shared__ unsigned vals[SUBCH];
  __shared__ unsigned char bb[SUBCH];
  __shared__ int hist[CBKT];
  __shared__ int gbase[CBKT];
  __shared__ int lbase[CBKT];
  int base = blockIdx.x * SUBCH;
  int cnt = E - base; if (cnt > SUBCH) cnt = SUBCH;
  int t = threadIdx.x;
  for (int i = t; i < CBKT; i += 256) hist[i] = 0;
  __syncthreads();
  int      myb[16];
  unsigned myv[16];
  #pragma unroll
  for (int j = 0; j < 16; j++){
    int i = t + j*256;
    if (i < cnt){
      int d  = dst[base+i];
      int s_ = src[base+i];
      int b  = d >> CB_BITS;
      myb[j] = b;
      myv[j] = ((unsigned)(d & ((1<<CB_BITS)-1)) << 18) | (unsigned)s_;
      atomicAdd(&hist[b], 1);
    } else myb[j] = -1;
  }
  __syncthreads();
  if (t == 0){
    int run = 0;
    for (int i = 0; i < CBKT; i++){ lbase[i] = run; run += hist[i]; }
  }
  __syncthreads();
  if (t < CBKT){
    int c = hist[t];
    gbase[t] = c ? atomicAdd(&gfill[t], c) : 0;
  }
  __syncthreads();
  if (t < CBKT) hist[t] = 0;           // reuse as local fill
  __syncthreads();
  #pragma unroll
  for (int j = 0; j < 16; j++){
    if (myb[j] >= 0){
      int pos = atomicAdd(&hist[myb[j]], 1);
      int idx = lbase[myb[j]] + pos;
      vals[idx] = myv[j];
      bb[idx]   = (unsigned char)myb[j];
    }
  }
  __syncthreads();
  #pragma unroll
  for (int j = 0; j < 16; j++){
    int i = t + j*256;
    if (i < cnt){
      int b = bb[i];
      pairbuf[gbase[b] + (i - lbase[b])] = vals[i];
    }
  }
}

// (4) per coarse bucket: count-sort over 1024 local nodes -> rowptr + colb.
// colb writes land in a ~65KB single-block window (one XCD's L2).
__global__ __launch_bounds__(256) void k_cfinal(const unsigned* __restrict__ pairbuf,
                                                const int* __restrict__ cbase,
                                                int* __restrict__ rowptr, int* __restrict__ colb){
  __shared__ int hist[1024];
  __shared__ int lbase[1024];
  __shared__ int partial[256];
  int b = blockIdx.x;
  int start = cbase[b], end = cbase[b+1];
  int t = threadIdx.x;
  #pragma unroll
  for (int j = 0; j < 4; j++) hist[t + j*256] = 0;
  __syncthreads();
  for (int k = start + t; k < end; k += 256)
    atomicAdd(&hist[pairbuf[k] >> 18], 1);
  __syncthreads();
  int h0 = hist[t*4], h1 = hist[t*4+1], h2 = hist[t*4+2], h3 = hist[t*4+3];
  int sum = h0+h1+h2+h3;
  partial[t] = sum;
  __syncthreads();
  #pragma unroll
  for (int off = 1; off < 256; off <<= 1){
    int u = (t >= off) ? partial[t-off] : 0;
    __syncthreads();
    partial[t] += u;
    __syncthreads();
  }
  int run = partial[t] - sum;
  lbase[t*4+0] = run; run += h0;
  lbase[t*4+1] = run; run += h1;
  lbase[t*4+2] = run; run += h2;
  lbase[t*4+3] = run;
  __syncthreads();
  int nodebase = b << CB_BITS;
  #pragma unroll
  for (int j = 0; j < 4; j++){
    int ln = t + j*256;
    int node = nodebase + ln;
    if (node < N_NODES_C) rowptr[node] = start + lbase[ln];
  }
  #pragma unroll
  for (int j = 0; j < 4; j++) hist[t + j*256] = 0;   // reuse as fill
  __syncthreads();
  for (int k = start + t; k < end; k += 256){
    unsigned v = pairbuf[k];
    int ln = v >> 18;
    int pos = atomicAdd(&hist[ln], 1);
    colb[start + lbase[ln] + pos] = (int)(v & 0x3FFFFu);
  }
}

// ---------------- node embedding ----------------
__global__ __launch_bounds__(256) void k_embed(const int* __restrict__ x, const float* __restrict__ emb,
                                               float* __restrict__ h, int total){
  int idx = blockIdx.x*256 + threadIdx.x;
  if (idx < total){
    int node = idx >> 6;
    h[idx] = emb[x[node]*64 + (idx & 63)];
  }
}

// ---------------- gather: z[i] = h[i] + sum_{j in N(i)} h[j] ----------------
// wave per node; lane = (edge_slot 0..3) x (float4 chunk 0..15); 32 edges in flight/iter.
__global__ __launch_bounds__(256) void k_gather(const float4* __restrict__ h4, const int* __restrict__ rowptr,
                                                const int* __restrict__ colb, float4* __restrict__ z4, int n){
  int wid   = __builtin_amdgcn_readfirstlane((int)(threadIdx.x >> 6));
  int lane  = threadIdx.x & 63;
  int eslot = lane >> 4;      // 0..3
  int c4    = lane & 15;      // float4 chunk
  int i = blockIdx.x*4 + wid;
  if (i >= n) return;
  int rs = rowptr[i], re = rowptr[i+1];
  float4 acc = make_float4(0.f, 0.f, 0.f, 0.f);
  for (int p = rs; p < re; p += 32){
    #pragma unroll
    for (int g = 0; g < 8; ++g){
      int e = p + g*4 + eslot;
      if (e < re){
        int c = colb[e];                      // broadcast within 16-lane group
        float4 v = h4[(size_t)c*16 + c4];
        acc.x += v.x; acc.y += v.y; acc.z += v.z; acc.w += v.w;
      }
    }
  }
  #pragma unroll
  for (int m = 16; m <= 32; m <<= 1){
    acc.x += __shfl_xor(acc.x, m, 64);
    acc.y += __shfl_xor(acc.y, m, 64);
    acc.z += __shfl_xor(acc.z, m, 64);
    acc.w += __shfl_xor(acc.w, m, 64);
  }
  if (eslot == 0){
    float4 s = h4[(size_t)i*16 + c4];
    acc.x += s.x; acc.y += s.y; acc.z += s.z; acc.w += s.w;
    z4[(size_t)i*16 + c4] = acc;
  }
}

// ---------------- per-node MLP: z <- relu(z@W1+b1)@W2+b2, in place ----------------
__global__ __launch_bounds__(256) void k_mlp(float* __restrict__ z,
                                             const float* __restrict__ w1, const float* __restrict__ b1,
                                             const float* __restrict__ w2, const float* __restrict__ b2, int n){
  int node = blockIdx.x*256 + threadIdx.x;
  if (node >= n) return;
  float* zrow = z + (size_t)node*64;
  float t[64];
  #pragma unroll
  for (int j = 0; j < 64; j++) t[j] = b1[j];
  for (int kb = 0; kb < 16; ++kb){
    float4 c = *reinterpret_cast<const float4*>(zrow + kb*4);
    const float* wr = w1 + kb*256;            // rows 4kb..4kb+3 of W1 (uniform -> s_load)
    #pragma unroll
    for (int j = 0; j < 64; j++)
      t[j] += c.x*wr[j] + c.y*wr[64+j] + c.z*wr[128+j] + c.w*wr[192+j];
  }
  #pragma unroll
  for (int j = 0; j < 64; j++) t[j] = fmaxf(t[j], 0.f);
  for (int jb = 0; jb < 16; ++jb){
    const float* wc = w2 + jb*4;              // column block jb (uniform -> s_load)
    float4 a = make_float4(b2[jb*4], b2[jb*4+1], b2[jb*4+2], b2[jb*4+3]);
    #pragma unroll
    for (int k = 0; k < 64; k++){
      a.x += t[k]*wc[k*64+0];
      a.y += t[k]*wc[k*64+1];
      a.z += t[k]*wc[k*64+2];
      a.w += t[k]*wc[k*64+3];
    }
    *reinterpret_cast<float4*>(zrow + jb*4) = a;
  }
}

// ---------------- global_add_pool (batch is sorted) ----------------
__global__ __launch_bounds__(256) void k_pool(const float* __restrict__ h, const int* __restrict__ batch,
                                              float* __restrict__ g, int n, int ng){
  int wid  = __builtin_amdgcn_readfirstlane((int)(threadIdx.x >> 6));
  int lane = threadIdx.x & 63;
  int gi = blockIdx.x*4 + wid;
  if (gi >= ng) return;
  int lo = 0, hi = n;
  while (lo < hi){ int m = (lo + hi) >> 1; if (batch[m] < gi) lo = m + 1; else hi = m; }
  int s = lo;
  hi = n;
  while (lo < hi){ int m = (lo + hi) >> 1; if (batch[m] < gi + 1) lo = m + 1; else hi = m; }
  int t = lo;
  float a0=0,a1=0,a2=0,a3=0;
  for (int p = s; p < t; p += 4){
    a0 += h[(size_t)p*64 + lane];
    if (p+1 < t) a1 += h[(size_t)(p+1)*64 + lane];
    if (p+2 < t) a2 += h[(size_t)(p+2)*64 + lane];
    if (p+3 < t) a3 += h[(size_t)(p+3)*64 + lane];
  }
  g[(size_t)gi*64 + lane] = (a0+a1) + (a2+a3);
}

// ---------------- readout MLP 64->32->16->1 ----------------
__global__ __launch_bounds__(256) void k_readout(const float* __restrict__ g,
                                                 const float* __restrict__ w1, const float* __restrict__ b1,
                                                 const float* __restrict__ w2, const float* __restrict__ b2,
                                                 const float* __restrict__ w3, const float* __restrict__ b3,
                                                 float* __restrict__ out, int ng){
  int gi = blockIdx.x*256 + threadIdx.x;
  if (gi >= ng) return;
  const float* gr = g + (size_t)gi*64;
  float a1[32];
  #pragma unroll
  for (int j = 0; j < 32; j++) a1[j] = b1[j];
  for (int k = 0; k < 64; k++){
    float gv = gr[k];
    const float* wr = w1 + k*32;
    #pragma unroll
    for (int j = 0; j < 32; j++) a1[j] += gv * wr[j];
  }
  float a2[16];
  #pragma unroll
  for (int j = 0; j < 16; j++) a2[j] = b2[j];
  #pragma unroll
  for (int k = 0; k < 32; k++){
    float t = fmaxf(a1[k], 0.f);
    const float* wr = w2 + k*16;
    #pragma unroll
    for (int j = 0; j < 16; j++) a2[j] += t * wr[j];
  }
  float r = b3[0];
  #pragma unroll
  for (int k = 0; k < 16; k++) r += fmaxf(a2[k], 0.f) * w3[k];
  out[gi] = r;
}

extern "C" void kernel_launch(void* const* d_in, const int* in_sizes, int n_in,
                              void* d_out, int out_size, void* d_ws, size_t ws_size,
                              hipStream_t stream){
  const int N = N_NODES_C, E = N_EDGES_C, G = NUM_GRAPHS_C;
  const int*   x     = (const int*)d_in[0];
  const int*   ei    = (const int*)d_in[1];   // [2,E]: src = ei[0..E), dst = ei[E..2E)
  const int*   batch = (const int*)d_in[3];
  const float* nemb  = (const float*)d_in[4];
  const float* cw1   = (const float*)d_in[6];
  const float* cb1   = (const float*)d_in[7];
  const float* cw2   = (const float*)d_in[8];
  const float* cb2   = (const float*)d_in[9];
  const float* mw1   = (const float*)d_in[10];
  const float* mb1   = (const float*)d_in[11];
  const float* mw2   = (const float*)d_in[12];
  const float* mb2   = (const float*)d_in[13];
  const float* mw3   = (const float*)d_in[14];
  const float* mb3   = (const float*)d_in[15];
  float* out = (float*)d_out;

  // Workspace (~116 MB, under the ~118.7 MB known-good bound).
  // pairbuf ALIASES hB: dead after k_cfinal; hB first written by layer-0 gather.
  char* cur = (char*)d_ws;
  auto take = [&](size_t bytes)->char*{
    char* p = cur; cur += (bytes + 255) & ~(size_t)255; return p;
  };
  int*      cbase   = (int*)  take((size_t)(CBKT+1)*4);
  int*      gfill   = (int*)  take((size_t)CBKT*4);
  int*      rowptr  = (int*)  take((size_t)(N+1)*4);
  int*      colb    = (int*)  take((size_t)(E+8)*4);
  float*    hA      = (float*)take((size_t)N*64*4);
  float*    hB      = (float*)take((size_t)N*64*4);
  float*    gbuf    = (float*)take((size_t)G*64*4);
  unsigned* pairbuf = (unsigned*)hB;          // alias: E*4 = 12.8MB <= 51.2MB

  hipMemsetAsync(cbase, 0, (size_t)(CBKT+1)*4, stream);

  const int CBIN_B = (E + SUBCH - 1)/SUBCH;         // 782
  k_chist <<<128, 256, 0, stream>>>(ei + E, cbase, E);
  k_cscan <<<1, 256, 0, stream>>>(cbase, gfill, rowptr);
  k_cbin  <<<CBIN_B, 256, 0, stream>>>(ei, ei + E, gfill, pairbuf, E);
  k_cfinal<<<CBKT, 256, 0, stream>>>(pairbuf, cbase, rowptr, colb);
  k_embed <<<(N*64 + 255)/256, 256, 0, stream>>>(x, nemb, hA, N*64);

  float* A = hA; float* B = hB;
  for (int l = 0; l < 4; l++){
    k_gather<<<(N + 3)/4, 256, 0, stream>>>((const float4*)A, rowptr, colb, (float4*)B, N);
    k_mlp   <<<(N + 255)/256, 256, 0, stream>>>(B, cw1 + l*4096, cb1 + l*64,
                                                cw2 + l*4096, cb2 + l*64, N);
    float* t2 = A; A = B; B = t2;
  }
  k_pool   <<<(G + 3)/4, 256, 0, stream>>>(A, batch, gbuf, N, G);
  k_readout<<<(G + 255)/256, 256, 0, stream>>>(gbuf, mw1, mb1, mw2, mb2, mw3, mb3, out, G);
}

// Round 11
// 1272.390 us; speedup vs baseline: 1.1868x; 1.0086x over previous
//
#include <hip/hip_runtime.h>

#define N_NODES_C 200000
#define N_EDGES_C 3200000
#define NUM_GRAPHS_C 1024
#define CB_BITS 10
#define CBKT 196           // ceil(200000 / 1024)
#define SUBCH 4096
#define MTILE 128          // nodes per k_mlp block

// ---------------- CSR build: coarse-bucket LDS-staged binning ----------------

// (1) histogram of coarse buckets -> cbase (counts)
__global__ __launch_bounds__(256) void k_chist(const int* __restrict__ dst, int* __restrict__ cbase, int E){
  __shared__ int hist[CBKT];
  for (int i = threadIdx.x; i < CBKT; i += 256) hist[i] = 0;
  __syncthreads();
  for (int e = blockIdx.x*256 + threadIdx.x; e < E; e += gridDim.x*256)
    atomicAdd(&hist[dst[e] >> CB_BITS], 1);
  __syncthreads();
  for (int i = threadIdx.x; i < CBKT; i += 256){
    int v = hist[i];
    if (v) atomicAdd(&cbase[i], v);
  }
}

// (2) exclusive scan of 196 counts; cbase <- bases, gfill <- bases, sentinels
__global__ __launch_bounds__(256) void k_cscan(int* __restrict__ cbase, int* __restrict__ gfill,
                                               int* __restrict__ rowptr){
  __shared__ int s[256];
  int t = threadIdx.x;
  int v = (t < CBKT) ? cbase[t] : 0;
  s[t] = v;
  __syncthreads();
  #pragma unroll
  for (int off = 1; off < 256; off <<= 1){
    int u = (t >= off) ? s[t - off] : 0;
    __syncthreads();
    s[t] += u;
    __syncthreads();
  }
  int excl = s[t] - v;
  if (t < CBKT){ cbase[t] = excl; gfill[t] = excl; }
  if (t == 0){ cbase[CBKT] = N_EDGES_C; rowptr[N_NODES_C] = N_EDGES_C; }
}

// (3) LDS-staged binning: each block reorders a 4096-edge sub-chunk by coarse
// bucket and writes per-bucket runs coalesced (each 64B line produced by one
// block's contiguous store -> no cross-XCD frontier ping-pong).
__global__ __launch_bounds__(256) void k_cbin(const int* __restrict__ src, const int* __restrict__ dst,
                                              int* __restrict__ gfill, unsigned* __restrict__ pairbuf, int E){
  __shared__ unsigned vals[SUBCH];
  __shared__ unsigned char bb[SUBCH];
  __shared__ int hist[CBKT];
  __shared__ int gbase[CBKT];
  __shared__ int lbase[CBKT];
  int base = blockIdx.x * SUBCH;
  int cnt = E - base; if (cnt > SUBCH) cnt = SUBCH;
  int t = threadIdx.x;
  for (int i = t; i < CBKT; i += 256) hist[i] = 0;
  __syncthreads();
  int      myb[16];
  unsigned myv[16];
  #pragma unroll
  for (int j = 0; j < 16; j++){
    int i = t + j*256;
    if (i < cnt){
      int d  = dst[base+i];
      int s_ = src[base+i];
      int b  = d >> CB_BITS;
      myb[j] = b;
      myv[j] = ((unsigned)(d & ((1<<CB_BITS)-1)) << 18) | (unsigned)s_;
      atomicAdd(&hist[b], 1);
    } else myb[j] = -1;
  }
  __syncthreads();
  if (t == 0){
    int run = 0;
    for (int i = 0; i < CBKT; i++){ lbase[i] = run; run += hist[i]; }
  }
  __syncthreads();
  if (t < CBKT){
    int c = hist[t];
    gbase[t] = c ? atomicAdd(&gfill[t], c) : 0;
  }
  __syncthreads();
  if (t < CBKT) hist[t] = 0;           // reuse as local fill
  __syncthreads();
  #pragma unroll
  for (int j = 0; j < 16; j++){
    if (myb[j] >= 0){
      int pos = atomicAdd(&hist[myb[j]], 1);
      int idx = lbase[myb[j]] + pos;
      vals[idx] = myv[j];
      bb[idx]   = (unsigned char)myb[j];
    }
  }
  __syncthreads();
  #pragma unroll
  for (int j = 0; j < 16; j++){
    int i = t + j*256;
    if (i < cnt){
      int b = bb[i];
      pairbuf[gbase[b] + (i - lbase[b])] = vals[i];
    }
  }
}

// (4) per coarse bucket: count-sort over 1024 local nodes -> rowptr + colb.
__global__ __launch_bounds__(256) void k_cfinal(const unsigned* __restrict__ pairbuf,
                                                const int* __restrict__ cbase,
                                                int* __restrict__ rowptr, int* __restrict__ colb){
  __shared__ int hist[1024];
  __shared__ int lbase[1024];
  __shared__ int partial[256];
  int b = blockIdx.x;
  int start = cbase[b], end = cbase[b+1];
  int t = threadIdx.x;
  #pragma unroll
  for (int j = 0; j < 4; j++) hist[t + j*256] = 0;
  __syncthreads();
  for (int k = start + t; k < end; k += 256)
    atomicAdd(&hist[pairbuf[k] >> 18], 1);
  __syncthreads();
  int h0 = hist[t*4], h1 = hist[t*4+1], h2 = hist[t*4+2], h3 = hist[t*4+3];
  int sum = h0+h1+h2+h3;
  partial[t] = sum;
  __syncthreads();
  #pragma unroll
  for (int off = 1; off < 256; off <<= 1){
    int u = (t >= off) ? partial[t-off] : 0;
    __syncthreads();
    partial[t] += u;
    __syncthreads();
  }
  int run = partial[t] - sum;
  lbase[t*4+0] = run; run += h0;
  lbase[t*4+1] = run; run += h1;
  lbase[t*4+2] = run; run += h2;
  lbase[t*4+3] = run;
  __syncthreads();
  int nodebase = b << CB_BITS;
  #pragma unroll
  for (int j = 0; j < 4; j++){
    int ln = t + j*256;
    int node = nodebase + ln;
    if (node < N_NODES_C) rowptr[node] = start + lbase[ln];
  }
  #pragma unroll
  for (int j = 0; j < 4; j++) hist[t + j*256] = 0;   // reuse as fill
  __syncthreads();
  for (int k = start + t; k < end; k += 256){
    unsigned v = pairbuf[k];
    int ln = v >> 18;
    int pos = atomicAdd(&hist[ln], 1);
    colb[start + lbase[ln] + pos] = (int)(v & 0x3FFFFu);
  }
}

// ---------------- node embedding ----------------
__global__ __launch_bounds__(256) void k_embed(const int* __restrict__ x, const float* __restrict__ emb,
                                               float* __restrict__ h, int total){
  int idx = blockIdx.x*256 + threadIdx.x;
  if (idx < total){
    int node = idx >> 6;
    h[idx] = emb[x[node]*64 + (idx & 63)];
  }
}

// ---------------- gather: z[i] = h[i] + sum_{j in N(i)} h[j] ----------------
// wave per node; lane = (edge_slot 0..3) x (float4 chunk 0..15); 32 edges in flight/iter.
__global__ __launch_bounds__(256) void k_gather(const float4* __restrict__ h4, const int* __restrict__ rowptr,
                                                const int* __restrict__ colb, float4* __restrict__ z4, int n){
  int wid   = __builtin_amdgcn_readfirstlane((int)(threadIdx.x >> 6));
  int lane  = threadIdx.x & 63;
  int eslot = lane >> 4;      // 0..3
  int c4    = lane & 15;      // float4 chunk
  int i = blockIdx.x*4 + wid;
  if (i >= n) return;
  int rs = rowptr[i], re = rowptr[i+1];
  float4 acc = make_float4(0.f, 0.f, 0.f, 0.f);
  for (int p = rs; p < re; p += 32){
    #pragma unroll
    for (int g = 0; g < 8; ++g){
      int e = p + g*4 + eslot;
      if (e < re){
        int c = colb[e];                      // broadcast within 16-lane group
        float4 v = h4[(size_t)c*16 + c4];
        acc.x += v.x; acc.y += v.y; acc.z += v.z; acc.w += v.w;
      }
    }
  }
  #pragma unroll
  for (int m = 16; m <= 32; m <<= 1){
    acc.x += __shfl_xor(acc.x, m, 64);
    acc.y += __shfl_xor(acc.y, m, 64);
    acc.z += __shfl_xor(acc.z, m, 64);
    acc.w += __shfl_xor(acc.w, m, 64);
  }
  if (eslot == 0){
    float4 s = h4[(size_t)i*16 + c4];
    acc.x += s.x; acc.y += s.y; acc.z += s.z; acc.w += s.w;
    z4[(size_t)i*16 + c4] = acc;
  }
}

// ---------------- per-node MLP, tiled: coalesced global <-> transposed LDS ----
// zt[k][node], pad 129: load/store banks (4(t%16)+t/16+..)%32 -> 2-way (free);
// compute banks (k+t)%32 -> 2-way (free). Thread t owns LDS column t during
// compute (reads z col t, writes out col t) -> no barrier inside compute.
__global__ __launch_bounds__(128) void k_mlp(float* __restrict__ z,
                                             const float* __restrict__ w1, const float* __restrict__ b1,
                                             const float* __restrict__ w2, const float* __restrict__ b2, int n){
  __shared__ float zt[64][MTILE + 1];
  int t = threadIdx.x;
  int base = blockIdx.x * MTILE;
  int tile_n = n - base; if (tile_n > MTILE) tile_n = MTILE;
  int lim4 = tile_n * 16;                    // float4 count in tile
  const float4* zin = (const float4*)(z + (size_t)base*64);
  #pragma unroll
  for (int i = 0; i < 16; i++){
    int f4 = i*128 + t;
    if (f4 < lim4){
      float4 v = zin[f4];
      int node = f4 >> 4;
      int k0 = (f4 & 15) << 2;
      zt[k0+0][node] = v.x;
      zt[k0+1][node] = v.y;
      zt[k0+2][node] = v.z;
      zt[k0+3][node] = v.w;
    }
  }
  __syncthreads();
  if (t < tile_n){
    float acc[64];
    #pragma unroll
    for (int j = 0; j < 64; j++) acc[j] = b1[j];
    for (int kb = 0; kb < 16; ++kb){
      float c0 = zt[kb*4+0][t], c1 = zt[kb*4+1][t], c2 = zt[kb*4+2][t], c3 = zt[kb*4+3][t];
      const float* wr = w1 + kb*256;         // rows 4kb..4kb+3 of W1 (uniform -> s_load)
      #pragma unroll
      for (int j = 0; j < 64; j++)
        acc[j] += c0*wr[j] + c1*wr[64+j] + c2*wr[128+j] + c3*wr[192+j];
    }
    #pragma unroll
    for (int j = 0; j < 64; j++) acc[j] = fmaxf(acc[j], 0.f);
    for (int jb = 0; jb < 16; ++jb){
      const float* wc = w2 + jb*4;           // column block jb (uniform -> s_load)
      float4 a = make_float4(b2[jb*4], b2[jb*4+1], b2[jb*4+2], b2[jb*4+3]);
      #pragma unroll
      for (int k = 0; k < 64; k++){
        a.x += acc[k]*wc[k*64+0];
        a.y += acc[k]*wc[k*64+1];
        a.z += acc[k]*wc[k*64+2];
        a.w += acc[k]*wc[k*64+3];
      }
      zt[jb*4+0][t] = a.x;                   // own column: no barrier needed
      zt[jb*4+1][t] = a.y;
      zt[jb*4+2][t] = a.z;
      zt[jb*4+3][t] = a.w;
    }
  }
  __syncthreads();
  float4* zout = (float4*)(z + (size_t)base*64);
  #pragma unroll
  for (int i = 0; i < 16; i++){
    int f4 = i*128 + t;
    if (f4 < lim4){
      int node = f4 >> 4;
      int k0 = (f4 & 15) << 2;
      zout[f4] = make_float4(zt[k0+0][node], zt[k0+1][node], zt[k0+2][node], zt[k0+3][node]);
    }
  }
}

// ---------------- global_add_pool (batch is sorted) ----------------
__global__ __launch_bounds__(256) void k_pool(const float* __restrict__ h, const int* __restrict__ batch,
                                              float* __restrict__ g, int n, int ng){
  int wid  = __builtin_amdgcn_readfirstlane((int)(threadIdx.x >> 6));
  int lane = threadIdx.x & 63;
  int gi = blockIdx.x*4 + wid;
  if (gi >= ng) return;
  int lo = 0, hi = n;
  while (lo < hi){ int m = (lo + hi) >> 1; if (batch[m] < gi) lo = m + 1; else hi = m; }
  int s = lo;
  hi = n;
  while (lo < hi){ int m = (lo + hi) >> 1; if (batch[m] < gi + 1) lo = m + 1; else hi = m; }
  int t = lo;
  float a0=0,a1=0,a2=0,a3=0;
  for (int p = s; p < t; p += 4){
    a0 += h[(size_t)p*64 + lane];
    if (p+1 < t) a1 += h[(size_t)(p+1)*64 + lane];
    if (p+2 < t) a2 += h[(size_t)(p+2)*64 + lane];
    if (p+3 < t) a3 += h[(size_t)(p+3)*64 + lane];
  }
  g[(size_t)gi*64 + lane] = (a0+a1) + (a2+a3);
}

// ---------------- readout MLP 64->32->16->1 ----------------
__global__ __launch_bounds__(256) void k_readout(const float* __restrict__ g,
                                                 const float* __restrict__ w1, const float* __restrict__ b1,
                                                 const float* __restrict__ w2, const float* __restrict__ b2,
                                                 const float* __restrict__ w3, const float* __restrict__ b3,
                                                 float* __restrict__ out, int ng){
  int gi = blockIdx.x*256 + threadIdx.x;
  if (gi >= ng) return;
  const float* gr = g + (size_t)gi*64;
  float a1[32];
  #pragma unroll
  for (int j = 0; j < 32; j++) a1[j] = b1[j];
  for (int k = 0; k < 64; k++){
    float gv = gr[k];
    const float* wr = w1 + k*32;
    #pragma unroll
    for (int j = 0; j < 32; j++) a1[j] += gv * wr[j];
  }
  float a2[16];
  #pragma unroll
  for (int j = 0; j < 16; j++) a2[j] = b2[j];
  #pragma unroll
  for (int k = 0; k < 32; k++){
    float t = fmaxf(a1[k], 0.f);
    const float* wr = w2 + k*16;
    #pragma unroll
    for (int j = 0; j < 16; j++) a2[j] += t * wr[j];
  }
  float r = b3[0];
  #pragma unroll
  for (int k = 0; k < 16; k++) r += fmaxf(a2[k], 0.f) * w3[k];
  out[gi] = r;
}

extern "C" void kernel_launch(void* const* d_in, const int* in_sizes, int n_in,
                              void* d_out, int out_size, void* d_ws, size_t ws_size,
                              hipStream_t stream){
  const int N = N_NODES_C, E = N_EDGES_C, G = NUM_GRAPHS_C;
  const int*   x     = (const int*)d_in[0];
  const int*   ei    = (const int*)d_in[1];   // [2,E]: src = ei[0..E), dst = ei[E..2E)
  const int*   batch = (const int*)d_in[3];
  const float* nemb  = (const float*)d_in[4];
  const float* cw1   = (const float*)d_in[6];
  const float* cb1   = (const float*)d_in[7];
  const float* cw2   = (const float*)d_in[8];
  const float* cb2   = (const float*)d_in[9];
  const float* mw1   = (const float*)d_in[10];
  const float* mb1   = (const float*)d_in[11];
  const float* mw2   = (const float*)d_in[12];
  const float* mb2   = (const float*)d_in[13];
  const float* mw3   = (const float*)d_in[14];
  const float* mb3   = (const float*)d_in[15];
  float* out = (float*)d_out;

  // Workspace (~116 MB, under the ~118.7 MB known-good bound).
  // pairbuf ALIASES hB: dead after k_cfinal; hB first written by layer-0 gather.
  char* cur = (char*)d_ws;
  auto take = [&](size_t bytes)->char*{
    char* p = cur; cur += (bytes + 255) & ~(size_t)255; return p;
  };
  int*      cbase   = (int*)  take((size_t)(CBKT+1)*4);
  int*      gfill   = (int*)  take((size_t)CBKT*4);
  int*      rowptr  = (int*)  take((size_t)(N+1)*4);
  int*      colb    = (int*)  take((size_t)(E+8)*4);
  float*    hA      = (float*)take((size_t)N*64*4);
  float*    hB      = (float*)take((size_t)N*64*4);
  float*    gbuf    = (float*)take((size_t)G*64*4);
  unsigned* pairbuf = (unsigned*)hB;          // alias: E*4 = 12.8MB <= 51.2MB

  hipMemsetAsync(cbase, 0, (size_t)(CBKT+1)*4, stream);

  const int CBIN_B = (E + SUBCH - 1)/SUBCH;         // 782
  k_chist <<<128, 256, 0, stream>>>(ei + E, cbase, E);
  k_cscan <<<1, 256, 0, stream>>>(cbase, gfill, rowptr);
  k_cbin  <<<CBIN_B, 256, 0, stream>>>(ei, ei + E, gfill, pairbuf, E);
  k_cfinal<<<CBKT, 256, 0, stream>>>(pairbuf, cbase, rowptr, colb);
  k_embed <<<(N*64 + 255)/256, 256, 0, stream>>>(x, nemb, hA, N*64);

  float* A = hA; float* B = hB;
  for (int l = 0; l < 4; l++){
    k_gather<<<(N + 3)/4, 256, 0, stream>>>((const float4*)A, rowptr, colb, (float4*)B, N);
    k_mlp   <<<(N + MTILE - 1)/MTILE, 128, 0, stream>>>(B, cw1 + l*4096, cb1 + l*64,
                                                        cw2 + l*4096, cb2 + l*64, N);
    float* t2 = A; A = B; B = t2;
  }
  k_pool   <<<(G + 3)/4, 256, 0, stream>>>(A, batch, gbuf, N, G);
  k_readout<<<(G + 255)/256, 256, 0, stream>>>(gbuf, mw1, mb1, mw2, mb2, mw3, mb3, out, G);
}

// Round 12
// 1153.871 us; speedup vs baseline: 1.3087x; 1.1027x over previous
//
#include <hip/hip_runtime.h>

#define N_NODES_C 200000
#define N_EDGES_C 3200000
#define NUM_GRAPHS_C 1024
#define CB_BITS 10
#define CBKT 196           // ceil(200000 / 1024)
#define SUBCH 4096
#define MTILE 128          // nodes per k_mlp block

// ---------------- CSR build: coarse-bucket LDS-staged binning ----------------

// (1) histogram of coarse buckets -> cbase (counts)
__global__ __launch_bounds__(256) void k_chist(const int* __restrict__ dst, int* __restrict__ cbase, int E){
  __shared__ int hist[CBKT];
  for (int i = threadIdx.x; i < CBKT; i += 256) hist[i] = 0;
  __syncthreads();
  for (int e = blockIdx.x*256 + threadIdx.x; e < E; e += gridDim.x*256)
    atomicAdd(&hist[dst[e] >> CB_BITS], 1);
  __syncthreads();
  for (int i = threadIdx.x; i < CBKT; i += 256){
    int v = hist[i];
    if (v) atomicAdd(&cbase[i], v);
  }
}

// (2) exclusive scan of 196 counts; cbase <- bases, gfill <- bases, sentinels
__global__ __launch_bounds__(256) void k_cscan(int* __restrict__ cbase, int* __restrict__ gfill,
                                               int* __restrict__ rowptr){
  __shared__ int s[256];
  int t = threadIdx.x;
  int v = (t < CBKT) ? cbase[t] : 0;
  s[t] = v;
  __syncthreads();
  #pragma unroll
  for (int off = 1; off < 256; off <<= 1){
    int u = (t >= off) ? s[t - off] : 0;
    __syncthreads();
    s[t] += u;
    __syncthreads();
  }
  int excl = s[t] - v;
  if (t < CBKT){ cbase[t] = excl; gfill[t] = excl; }
  if (t == 0){ cbase[CBKT] = N_EDGES_C; rowptr[N_NODES_C] = N_EDGES_C; }
}

// (3) LDS-staged binning: each block reorders a 4096-edge sub-chunk by coarse
// bucket and writes per-bucket runs coalesced (each 64B line produced by one
// block's contiguous store -> no cross-XCD frontier ping-pong).
__global__ __launch_bounds__(256) void k_cbin(const int* __restrict__ src, const int* __restrict__ dst,
                                              int* __restrict__ gfill, unsigned* __restrict__ pairbuf, int E){
  __shared__ unsigned vals[SUBCH];
  __shared__ unsigned char bb[SUBCH];
  __shared__ int hist[CBKT];
  __shared__ int gbase[CBKT];
  __shared__ int lbase[CBKT];
  int base = blockIdx.x * SUBCH;
  int cnt = E - base; if (cnt > SUBCH) cnt = SUBCH;
  int t = threadIdx.x;
  for (int i = t; i < CBKT; i += 256) hist[i] = 0;
  __syncthreads();
  int      myb[16];
  unsigned myv[16];
  #pragma unroll
  for (int j = 0; j < 16; j++){
    int i = t + j*256;
    if (i < cnt){
      int d  = dst[base+i];
      int s_ = src[base+i];
      int b  = d >> CB_BITS;
      myb[j] = b;
      myv[j] = ((unsigned)(d & ((1<<CB_BITS)-1)) << 18) | (unsigned)s_;
      atomicAdd(&hist[b], 1);
    } else myb[j] = -1;
  }
  __syncthreads();
  if (t == 0){
    int run = 0;
    for (int i = 0; i < CBKT; i++){ lbase[i] = run; run += hist[i]; }
  }
  __syncthreads();
  if (t < CBKT){
    int c = hist[t];
    gbase[t] = c ? atomicAdd(&gfill[t], c) : 0;
  }
  __syncthreads();
  if (t < CBKT) hist[t] = 0;           // reuse as local fill
  __syncthreads();
  #pragma unroll
  for (int j = 0; j < 16; j++){
    if (myb[j] >= 0){
      int pos = atomicAdd(&hist[myb[j]], 1);
      int idx = lbase[myb[j]] + pos;
      vals[idx] = myv[j];
      bb[idx]   = (unsigned char)myb[j];
    }
  }
  __syncthreads();
  #pragma unroll
  for (int j = 0; j < 16; j++){
    int i = t + j*256;
    if (i < cnt){
      int b = bb[i];
      pairbuf[gbase[b] + (i - lbase[b])] = vals[i];
    }
  }
}

// (4) per coarse bucket: count-sort over 1024 local nodes -> rowptr + colb.
__global__ __launch_bounds__(256) void k_cfinal(const unsigned* __restrict__ pairbuf,
                                                const int* __restrict__ cbase,
                                                int* __restrict__ rowptr, int* __restrict__ colb){
  __shared__ int hist[1024];
  __shared__ int lbase[1024];
  __shared__ int partial[256];
  int b = blockIdx.x;
  int start = cbase[b], end = cbase[b+1];
  int t = threadIdx.x;
  #pragma unroll
  for (int j = 0; j < 4; j++) hist[t + j*256] = 0;
  __syncthreads();
  for (int k = start + t; k < end; k += 256)
    atomicAdd(&hist[pairbuf[k] >> 18], 1);
  __syncthreads();
  int h0 = hist[t*4], h1 = hist[t*4+1], h2 = hist[t*4+2], h3 = hist[t*4+3];
  int sum = h0+h1+h2+h3;
  partial[t] = sum;
  __syncthreads();
  #pragma unroll
  for (int off = 1; off < 256; off <<= 1){
    int u = (t >= off) ? partial[t-off] : 0;
    __syncthreads();
    partial[t] += u;
    __syncthreads();
  }
  int run = partial[t] - sum;
  lbase[t*4+0] = run; run += h0;
  lbase[t*4+1] = run; run += h1;
  lbase[t*4+2] = run; run += h2;
  lbase[t*4+3] = run;
  __syncthreads();
  int nodebase = b << CB_BITS;
  #pragma unroll
  for (int j = 0; j < 4; j++){
    int ln = t + j*256;
    int node = nodebase + ln;
    if (node < N_NODES_C) rowptr[node] = start + lbase[ln];
  }
  #pragma unroll
  for (int j = 0; j < 4; j++) hist[t + j*256] = 0;   // reuse as fill
  __syncthreads();
  for (int k = start + t; k < end; k += 256){
    unsigned v = pairbuf[k];
    int ln = v >> 18;
    int pos = atomicAdd(&hist[ln], 1);
    colb[start + lbase[ln] + pos] = (int)(v & 0x3FFFFu);
  }
}

// ---------------- node embedding ----------------
__global__ __launch_bounds__(256) void k_embed(const int* __restrict__ x, const float* __restrict__ emb,
                                               float* __restrict__ h, int total){
  int idx = blockIdx.x*256 + threadIdx.x;
  if (idx < total){
    int node = idx >> 6;
    h[idx] = emb[x[node]*64 + (idx & 63)];
  }
}

// ---------------- gather: z[i] = h[i] + sum_{j in N(i)} h[j] ----------------
// wave per node; lane = (edge_slot 0..3) x (float4 chunk 0..15); 32 edges in flight/iter.
__global__ __launch_bounds__(256) void k_gather(const float4* __restrict__ h4, const int* __restrict__ rowptr,
                                                const int* __restrict__ colb, float4* __restrict__ z4, int n){
  int wid   = __builtin_amdgcn_readfirstlane((int)(threadIdx.x >> 6));
  int lane  = threadIdx.x & 63;
  int eslot = lane >> 4;      // 0..3
  int c4    = lane & 15;      // float4 chunk
  int i = blockIdx.x*4 + wid;
  if (i >= n) return;
  int rs = rowptr[i], re = rowptr[i+1];
  float4 acc = make_float4(0.f, 0.f, 0.f, 0.f);
  for (int p = rs; p < re; p += 32){
    #pragma unroll
    for (int g = 0; g < 8; ++g){
      int e = p + g*4 + eslot;
      if (e < re){
        int c = colb[e];                      // broadcast within 16-lane group
        float4 v = h4[(size_t)c*16 + c4];
        acc.x += v.x; acc.y += v.y; acc.z += v.z; acc.w += v.w;
      }
    }
  }
  #pragma unroll
  for (int m = 16; m <= 32; m <<= 1){
    acc.x += __shfl_xor(acc.x, m, 64);
    acc.y += __shfl_xor(acc.y, m, 64);
    acc.z += __shfl_xor(acc.z, m, 64);
    acc.w += __shfl_xor(acc.w, m, 64);
  }
  if (eslot == 0){
    float4 s = h4[(size_t)i*16 + c4];
    acc.x += s.x; acc.y += s.y; acc.z += s.z; acc.w += s.w;
    z4[(size_t)i*16 + c4] = acc;
  }
}

// ---------------- per-node MLP, tiled + 32-channel chunked LDS ----------------
// zt[32][129] = 16.5 KB -> 9 blocks/CU = 18 waves/CU (was 33KB -> 8 waves, 18%
// occupancy, latency-bound at VALUBusy 26%). Two k-chunks for GEMM1 (same
// accumulation order -> bit-exact), two j-chunks for GEMM2+store. Compute
// phases touch only the thread's own LDS column -> fewer barriers.
__global__ __launch_bounds__(128, 4) void k_mlp(float* __restrict__ z,
                                                const float* __restrict__ w1, const float* __restrict__ b1,
                                                const float* __restrict__ w2, const float* __restrict__ b2, int n){
  __shared__ float zt[32][MTILE + 1];
  int t = threadIdx.x;
  int base = blockIdx.x * MTILE;
  int tile_n = n - base; if (tile_n > MTILE) tile_n = MTILE;
  int lim = tile_n * 8;                      // half-row float4 count in tile
  const float4* zin = (const float4*)(z + (size_t)base*64);
  float acc[64];
  #pragma unroll
  for (int j = 0; j < 64; j++) acc[j] = b1[j];

  // ---- GEMM1 in two 32-channel k-chunks ----
  #pragma unroll
  for (int ch = 0; ch < 2; ++ch){
    __syncthreads();                         // prior-phase readers done with zt
    #pragma unroll
    for (int i = 0; i < 8; i++){
      int f4 = i*128 + t;
      if (f4 < lim){
        int node = f4 >> 3;
        int c = f4 & 7;                      // f4-chunk within half-row
        float4 v = zin[node*16 + ch*8 + c];  // coalesced 128B half-rows
        zt[c*4+0][node] = v.x;
        zt[c*4+1][node] = v.y;
        zt[c*4+2][node] = v.z;
        zt[c*4+3][node] = v.w;
      }
    }
    __syncthreads();
    if (t < tile_n){
      for (int kb = 0; kb < 8; ++kb){        // own column reads only
        float c0 = zt[kb*4+0][t], c1 = zt[kb*4+1][t], c2 = zt[kb*4+2][t], c3 = zt[kb*4+3][t];
        const float* wr = w1 + (ch*8 + kb)*256;   // uniform -> s_load
        #pragma unroll
        for (int j = 0; j < 64; j++)
          acc[j] += c0*wr[j] + c1*wr[64+j] + c2*wr[128+j] + c3*wr[192+j];
      }
    }
  }
  #pragma unroll
  for (int j = 0; j < 64; j++) acc[j] = fmaxf(acc[j], 0.f);

  // ---- GEMM2 + store in two 32-channel j-chunks ----
  float4* zout = (float4*)(z + (size_t)base*64);
  #pragma unroll
  for (int ch = 0; ch < 2; ++ch){
    if (t < tile_n){
      for (int jb = 0; jb < 8; ++jb){
        int jj = ch*8 + jb;
        const float* wc = w2 + jj*4;         // uniform -> s_load
        float4 a = make_float4(b2[jj*4], b2[jj*4+1], b2[jj*4+2], b2[jj*4+3]);
        #pragma unroll
        for (int k = 0; k < 64; k++){
          a.x += acc[k]*wc[k*64+0];
          a.y += acc[k]*wc[k*64+1];
          a.z += acc[k]*wc[k*64+2];
          a.w += acc[k]*wc[k*64+3];
        }
        zt[jb*4+0][t] = a.x;                 // own column: no barrier needed
        zt[jb*4+1][t] = a.y;
        zt[jb*4+2][t] = a.z;
        zt[jb*4+3][t] = a.w;
      }
    }
    __syncthreads();                         // all columns written before store
    #pragma unroll
    for (int i = 0; i < 8; i++){
      int f4 = i*128 + t;
      if (f4 < lim){
        int node = f4 >> 3;
        int c = f4 & 7;
        zout[node*16 + ch*8 + c] =
            make_float4(zt[c*4+0][node], zt[c*4+1][node], zt[c*4+2][node], zt[c*4+3][node]);
      }
    }
    __syncthreads();                         // store done before zt reused
  }
}

// ---------------- global_add_pool (batch is sorted) ----------------
__global__ __launch_bounds__(256) void k_pool(const float* __restrict__ h, const int* __restrict__ batch,
                                              float* __restrict__ g, int n, int ng){
  int wid  = __builtin_amdgcn_readfirstlane((int)(threadIdx.x >> 6));
  int lane = threadIdx.x & 63;
  int gi = blockIdx.x*4 + wid;
  if (gi >= ng) return;
  int lo = 0, hi = n;
  while (lo < hi){ int m = (lo + hi) >> 1; if (batch[m] < gi) lo = m + 1; else hi = m; }
  int s = lo;
  hi = n;
  while (lo < hi){ int m = (lo + hi) >> 1; if (batch[m] < gi + 1) lo = m + 1; else hi = m; }
  int t = lo;
  float a0=0,a1=0,a2=0,a3=0;
  for (int p = s; p < t; p += 4){
    a0 += h[(size_t)p*64 + lane];
    if (p+1 < t) a1 += h[(size_t)(p+1)*64 + lane];
    if (p+2 < t) a2 += h[(size_t)(p+2)*64 + lane];
    if (p+3 < t) a3 += h[(size_t)(p+3)*64 + lane];
  }
  g[(size_t)gi*64 + lane] = (a0+a1) + (a2+a3);
}

// ---------------- readout MLP 64->32->16->1 ----------------
__global__ __launch_bounds__(256) void k_readout(const float* __restrict__ g,
                                                 const float* __restrict__ w1, const float* __restrict__ b1,
                                                 const float* __restrict__ w2, const float* __restrict__ b2,
                                                 const float* __restrict__ w3, const float* __restrict__ b3,
                                                 float* __restrict__ out, int ng){
  int gi = blockIdx.x*256 + threadIdx.x;
  if (gi >= ng) return;
  const float* gr = g + (size_t)gi*64;
  float a1[32];
  #pragma unroll
  for (int j = 0; j < 32; j++) a1[j] = b1[j];
  for (int k = 0; k < 64; k++){
    float gv = gr[k];
    const float* wr = w1 + k*32;
    #pragma unroll
    for (int j = 0; j < 32; j++) a1[j] += gv * wr[j];
  }
  float a2[16];
  #pragma unroll
  for (int j = 0; j < 16; j++) a2[j] = b2[j];
  #pragma unroll
  for (int k = 0; k < 32; k++){
    float t = fmaxf(a1[k], 0.f);
    const float* wr = w2 + k*16;
    #pragma unroll
    for (int j = 0; j < 16; j++) a2[j] += t * wr[j];
  }
  float r = b3[0];
  #pragma unroll
  for (int k = 0; k < 16; k++) r += fmaxf(a2[k], 0.f) * w3[k];
  out[gi] = r;
}

extern "C" void kernel_launch(void* const* d_in, const int* in_sizes, int n_in,
                              void* d_out, int out_size, void* d_ws, size_t ws_size,
                              hipStream_t stream){
  const int N = N_NODES_C, E = N_EDGES_C, G = NUM_GRAPHS_C;
  const int*   x     = (const int*)d_in[0];
  const int*   ei    = (const int*)d_in[1];   // [2,E]: src = ei[0..E), dst = ei[E..2E)
  const int*   batch = (const int*)d_in[3];
  const float* nemb  = (const float*)d_in[4];
  const float* cw1   = (const float*)d_in[6];
  const float* cb1   = (const float*)d_in[7];
  const float* cw2   = (const float*)d_in[8];
  const float* cb2   = (const float*)d_in[9];
  const float* mw1   = (const float*)d_in[10];
  const float* mb1   = (const float*)d_in[11];
  const float* mw2   = (const float*)d_in[12];
  const float* mb2   = (const float*)d_in[13];
  const float* mw3   = (const float*)d_in[14];
  const float* mb3   = (const float*)d_in[15];
  float* out = (float*)d_out;

  // Workspace (~116 MB, under the ~118.7 MB known-good bound).
  // pairbuf ALIASES hB: dead after k_cfinal; hB first written by layer-0 gather.
  char* cur = (char*)d_ws;
  auto take = [&](size_t bytes)->char*{
    char* p = cur; cur += (bytes + 255) & ~(size_t)255; return p;
  };
  int*      cbase   = (int*)  take((size_t)(CBKT+1)*4);
  int*      gfill   = (int*)  take((size_t)CBKT*4);
  int*      rowptr  = (int*)  take((size_t)(N+1)*4);
  int*      colb    = (int*)  take((size_t)(E+8)*4);
  float*    hA      = (float*)take((size_t)N*64*4);
  float*    hB      = (float*)take((size_t)N*64*4);
  float*    gbuf    = (float*)take((size_t)G*64*4);
  unsigned* pairbuf = (unsigned*)hB;          // alias: E*4 = 12.8MB <= 51.2MB

  hipMemsetAsync(cbase, 0, (size_t)(CBKT+1)*4, stream);

  const int CBIN_B = (E + SUBCH - 1)/SUBCH;         // 782
  k_chist <<<128, 256, 0, stream>>>(ei + E, cbase, E);
  k_cscan <<<1, 256, 0, stream>>>(cbase, gfill, rowptr);
  k_cbin  <<<CBIN_B, 256, 0, stream>>>(ei, ei + E, gfill, pairbuf, E);
  k_cfinal<<<CBKT, 256, 0, stream>>>(pairbuf, cbase, rowptr, colb);
  k_embed <<<(N*64 + 255)/256, 256, 0, stream>>>(x, nemb, hA, N*64);

  float* A = hA; float* B = hB;
  for (int l = 0; l < 4; l++){
    k_gather<<<(N + 3)/4, 256, 0, stream>>>((const float4*)A, rowptr, colb, (float4*)B, N);
    k_mlp   <<<(N + MTILE - 1)/MTILE, 128, 0, stream>>>(B, cw1 + l*4096, cb1 + l*64,
                                                        cw2 + l*4096, cb2 + l*64, N);
    float* t2 = A; A = B; B = t2;
  }
  k_pool   <<<(G + 3)/4, 256, 0, stream>>>(A, batch, gbuf, N, G);
  k_readout<<<(G + 255)/256, 256, 0, stream>>>(gbuf, mw1, mb1, mw2, mb2, mw3, mb3, out, G);
}